// Round 1
// baseline (1213.491 us; speedup 1.0000x reference)
//
#include <hip/hip_runtime.h>
#include <hip/hip_bf16.h>

#define NROWS 16384
#define DIM   1024

typedef __bf16 bf16x8 __attribute__((ext_vector_type(8)));
typedef float  f32x4  __attribute__((ext_vector_type(4)));

__device__ __forceinline__ void glds16(const void* g, void* l) {
    __builtin_amdgcn_global_load_lds(
        (const __attribute__((address_space(1))) void*)g,
        (__attribute__((address_space(3))) void*)l,
        16, 0, 0);
}

// One block per (row, tensor): fp32 L2-normalize -> bf16.
__global__ void norm_kernel(const float* __restrict__ img,
                            const float* __restrict__ txt,
                            __hip_bfloat16* __restrict__ imgN,
                            __hip_bfloat16* __restrict__ txtN,
                            float* __restrict__ accum) {
    __shared__ float wsum[4];
    __shared__ float inv_s;
    const int row   = blockIdx.x;
    const int which = blockIdx.y;
    const int t     = threadIdx.x;
    const int lane  = t & 63;
    const int wave  = t >> 6;

    if (row == 0 && which == 0 && t == 0) *accum = 0.0f;  // ws is poisoned each launch

    const float* src = which ? txt : img;
    __hip_bfloat16* dst = which ? txtN : imgN;

    // D=1024 == 256 threads * 4 floats: exactly one float4 per thread
    float4 v = ((const float4*)(src + (size_t)row * DIM))[t];
    float ss = v.x*v.x + v.y*v.y + v.z*v.z + v.w*v.w;
    #pragma unroll
    for (int off = 32; off > 0; off >>= 1) ss += __shfl_down(ss, off, 64);
    if (lane == 0) wsum[wave] = ss;
    __syncthreads();
    if (t == 0) {
        float tot = wsum[0] + wsum[1] + wsum[2] + wsum[3];
        inv_s = 1.0f / fmaxf(sqrtf(tot), 1e-12f);
    }
    __syncthreads();
    const float inv = inv_s;

    union { ushort4 u; __hip_bfloat16 h[4]; } pk;
    pk.h[0] = __float2bfloat16(v.x * inv);
    pk.h[1] = __float2bfloat16(v.y * inv);
    pk.h[2] = __float2bfloat16(v.z * inv);
    pk.h[3] = __float2bfloat16(v.w * inv);
    ((ushort4*)(dst + (size_t)row * DIM))[t] = pk.u;
}

// Fused C = A . B^T (both row-major [N,D] bf16) -> softplus epilogue -> scalar sum.
// 128x128 block tile, 256 threads = 4 waves in 2x2, each wave 4x4 of 16x16x32 MFMA.
__global__ __launch_bounds__(256) void siglip_gemm(
    const __hip_bfloat16* __restrict__ A,   // normalized image
    const __hip_bfloat16* __restrict__ B,   // normalized text
    const float* __restrict__ lscale,
    const float* __restrict__ lbias,
    float* __restrict__ accum)
{
    __shared__ __hip_bfloat16 sA[128 * 32];  // 8 KB, unpadded (global_load_lds lane-order)
    __shared__ __hip_bfloat16 sB[128 * 32];
    __shared__ float wred[4];

    const int t    = threadIdx.x;
    const int lane = t & 63;
    const int wave = t >> 6;
    const int wr   = wave >> 1;   // wave row within 2x2
    const int wc   = wave & 1;    // wave col
    const int q    = lane >> 4;   // quad 0..3 (k-chunk)
    const int l16  = lane & 15;

    // group-of-16-rows block swizzle for cache locality
    const int GRID = NROWS / 128;           // 128
    const int GM = 16;
    int b = blockIdx.x;
    int group = b / (GM * GRID);
    int ing   = b % (GM * GRID);
    int brow  = group * GM + (ing % GM);
    int bcol  = ing / GM;

    const size_t aBase = (size_t)brow * 128;
    const size_t bBase = (size_t)bcol * 128;

    // staging decomposition: lane i writes LDS at chunkBase + i*16
    const int srow   = lane >> 2;   // 0..15 row within 16-row chunk
    const int schunk = lane & 3;    // 16B chunk within a 64B row

    f32x4 acc[4][4] = {};

    for (int k0 = 0; k0 < DIM; k0 += 32) {
        __syncthreads();
        #pragma unroll
        for (int it = 0; it < 2; ++it) {
            int rchunk = it * 4 + wave;          // wave-uniform 16-row chunk id 0..7
            int row = rchunk * 16 + srow;        // 0..127
            char* lA = ((char*)sA) + rchunk * 1024;
            char* lB = ((char*)sB) + rchunk * 1024;
            glds16(A + (aBase + row) * DIM + k0 + schunk * 8, lA);
            glds16(B + (bBase + row) * DIM + k0 + schunk * 8, lB);
        }
        __syncthreads();

        bf16x8 af[4], bfr[4];
        #pragma unroll
        for (int mi = 0; mi < 4; ++mi)
            af[mi] = *(const bf16x8*)(sA + (wr * 64 + mi * 16 + l16) * 32 + q * 8);
        #pragma unroll
        for (int ni = 0; ni < 4; ++ni)
            bfr[ni] = *(const bf16x8*)(sB + (wc * 64 + ni * 16 + l16) * 32 + q * 8);

        #pragma unroll
        for (int mi = 0; mi < 4; ++mi)
            #pragma unroll
            for (int ni = 0; ni < 4; ++ni)
                acc[mi][ni] = __builtin_amdgcn_mfma_f32_16x16x32_bf16(
                    af[mi], bfr[ni], acc[mi][ni], 0, 0, 0);
    }

    // epilogue: z = scale*s + bias; y = label*z; elem = softplus(-y) = -log_sigmoid(y)
    const float scale = __expf(lscale[0]);
    const float bias  = lbias[0];
    float local = 0.0f;
    #pragma unroll
    for (int mi = 0; mi < 4; ++mi) {
        #pragma unroll
        for (int ni = 0; ni < 4; ++ni) {
            #pragma unroll
            for (int r = 0; r < 4; ++r) {
                // C/D layout: col = lane&15, row = (lane>>4)*4 + r  [m89/m91]
                long rowg = (long)(aBase + wr * 64 + mi * 16 + q * 4 + r);
                long colg = (long)(bBase + wc * 64 + ni * 16 + l16);
                float z = fmaf(scale, acc[mi][ni][r], bias);
                float y = (rowg == colg) ? z : -z;
                float tn = -y;
                local += fmaxf(tn, 0.0f) + log1pf(__expf(-fabsf(tn)));
            }
        }
    }

    #pragma unroll
    for (int off = 32; off > 0; off >>= 1) local += __shfl_down(local, off, 64);
    if (lane == 0) wred[wave] = local;
    __syncthreads();
    if (t == 0) atomicAdd(accum, wred[0] + wred[1] + wred[2] + wred[3]);
}

__global__ void finalize_kernel(const float* __restrict__ accum, float* __restrict__ out) {
    out[0] = accum[0] / 268435456.0f;   // / N^2
}

extern "C" void kernel_launch(void* const* d_in, const int* in_sizes, int n_in,
                              void* d_out, int out_size, void* d_ws, size_t ws_size,
                              hipStream_t stream) {
    const float* img    = (const float*)d_in[0];
    const float* txt    = (const float*)d_in[1];
    const float* lscale = (const float*)d_in[2];
    const float* lbias  = (const float*)d_in[3];
    float* out = (float*)d_out;

    char* ws = (char*)d_ws;
    __hip_bfloat16* imgN = (__hip_bfloat16*)ws;
    __hip_bfloat16* txtN = (__hip_bfloat16*)(ws + (size_t)NROWS * DIM * 2);
    float* accum = (float*)(ws + (size_t)NROWS * DIM * 4);

    norm_kernel<<<dim3(NROWS, 2), 256, 0, stream>>>(img, txt, imgN, txtN, accum);
    siglip_gemm<<<dim3((NROWS / 128) * (NROWS / 128)), 256, 0, stream>>>(
        imgN, txtN, lscale, lbias, accum);
    finalize_kernel<<<1, 1, 0, stream>>>(accum, out);
}

// Round 2
// 847.574 us; speedup vs baseline: 1.4317x; 1.4317x over previous
//
#include <hip/hip_runtime.h>
#include <hip/hip_bf16.h>

#define NROWS 16384
#define DIM   1024

typedef __bf16 bf16x8 __attribute__((ext_vector_type(8)));
typedef float  f32x4  __attribute__((ext_vector_type(4)));

__device__ __forceinline__ void glds16(const void* g, void* l) {
    __builtin_amdgcn_global_load_lds(
        (const __attribute__((address_space(1))) void*)g,
        (__attribute__((address_space(3))) void*)l,
        16, 0, 0);
}

__device__ __forceinline__ float fexp2(float x) {
#if __has_builtin(__builtin_amdgcn_exp2f)
    return __builtin_amdgcn_exp2f(x);
#else
    return exp2f(x);
#endif
}
__device__ __forceinline__ float flog2(float x) {
#if __has_builtin(__builtin_amdgcn_logf)
    return __builtin_amdgcn_logf(x);
#else
    return log2f(x);
#endif
}

// One block per (row, tensor): fp32 L2-normalize -> bf16.
__global__ void norm_kernel(const float* __restrict__ img,
                            const float* __restrict__ txt,
                            __hip_bfloat16* __restrict__ imgN,
                            __hip_bfloat16* __restrict__ txtN,
                            float* __restrict__ accum) {
    __shared__ float wsum[4];
    __shared__ float inv_s;
    const int row   = blockIdx.x;
    const int which = blockIdx.y;
    const int t     = threadIdx.x;
    const int lane  = t & 63;
    const int wave  = t >> 6;

    if (row == 0 && which == 0 && t == 0) *accum = 0.0f;  // ws is poisoned each launch

    const float* src = which ? txt : img;
    __hip_bfloat16* dst = which ? txtN : imgN;

    // D=1024 == 256 threads * 4 floats: exactly one float4 per thread
    float4 v = ((const float4*)(src + (size_t)row * DIM))[t];
    float ss = v.x*v.x + v.y*v.y + v.z*v.z + v.w*v.w;
    #pragma unroll
    for (int off = 32; off > 0; off >>= 1) ss += __shfl_down(ss, off, 64);
    if (lane == 0) wsum[wave] = ss;
    __syncthreads();
    if (t == 0) {
        float tot = wsum[0] + wsum[1] + wsum[2] + wsum[3];
        inv_s = 1.0f / fmaxf(sqrtf(tot), 1e-12f);
    }
    __syncthreads();
    const float inv = inv_s;

    union { ushort4 u; __hip_bfloat16 h[4]; } pk;
    pk.h[0] = __float2bfloat16(v.x * inv);
    pk.h[1] = __float2bfloat16(v.y * inv);
    pk.h[2] = __float2bfloat16(v.z * inv);
    pk.h[3] = __float2bfloat16(v.w * inv);
    ((ushort4*)(dst + (size_t)row * DIM))[t] = pk.u;
}

// Diagonal correction: accum += sum_i ( -z_ii ), z_ii = scale*dot(imgN_i,txtN_i)+bias.
// One wave per row; 4 rows per 256-thread block.
__global__ __launch_bounds__(256) void diag_kernel(
    const __hip_bfloat16* __restrict__ A,
    const __hip_bfloat16* __restrict__ B,
    const float* __restrict__ lscale,
    const float* __restrict__ lbias,
    float* __restrict__ accum) {
    __shared__ float wz[4];
    const int t    = threadIdx.x;
    const int lane = t & 63;
    const int wave = t >> 6;
    const size_t row = (size_t)blockIdx.x * 4 + wave;

    const __hip_bfloat16* a = A + row * DIM;
    const __hip_bfloat16* b = B + row * DIM;

    float dot = 0.0f;
    #pragma unroll
    for (int h = 0; h < 2; ++h) {
        // coalesced: lane i reads 16B at (h*512 + i*8) elements
        union { bf16x8 v; ushort u[8]; } ua, ub;
        ua.v = *(const bf16x8*)(a + h * 512 + lane * 8);
        ub.v = *(const bf16x8*)(b + h * 512 + lane * 8);
        #pragma unroll
        for (int e = 0; e < 8; ++e) {
            float fa = __uint_as_float((unsigned)ua.u[e] << 16);
            float fb = __uint_as_float((unsigned)ub.u[e] << 16);
            dot = fmaf(fa, fb, dot);
        }
    }
    #pragma unroll
    for (int off = 32; off > 0; off >>= 1) dot += __shfl_down(dot, off, 64);
    if (lane == 0) {
        float z = fmaf(__expf(lscale[0]), dot, lbias[0]);
        wz[wave] = z;
    }
    __syncthreads();
    if (t == 0) atomicAdd(accum, -(wz[0] + wz[1] + wz[2] + wz[3]));
}

// Fused C = A . B^T (both row-major [N,D] bf16) -> branchless softplus epilogue -> scalar sum.
// 128x128 block tile, 256 threads = 4 waves in 2x2, each wave 4x4 of 16x16x32 MFMA.
__global__ __launch_bounds__(256) void siglip_gemm(
    const __hip_bfloat16* __restrict__ A,   // normalized image
    const __hip_bfloat16* __restrict__ B,   // normalized text
    const float* __restrict__ lscale,
    const float* __restrict__ lbias,
    float* __restrict__ accum)
{
    __shared__ __hip_bfloat16 sA[128 * 32];  // 8 KB, unpadded (global_load_lds lane-order)
    __shared__ __hip_bfloat16 sB[128 * 32];
    __shared__ float wred[4];

    const int t    = threadIdx.x;
    const int lane = t & 63;
    const int wave = t >> 6;
    const int wr   = wave >> 1;   // wave row within 2x2
    const int wc   = wave & 1;    // wave col
    const int q    = lane >> 4;   // quad 0..3 (k-chunk)
    const int l16  = lane & 15;

    // group-of-16-rows block swizzle for cache locality
    const int GRID = NROWS / 128;           // 128
    const int GM = 16;
    int b = blockIdx.x;
    int group = b / (GM * GRID);
    int ing   = b % (GM * GRID);
    int brow  = group * GM + (ing % GM);
    int bcol  = ing / GM;

    const size_t aBase = (size_t)brow * 128;
    const size_t bBase = (size_t)bcol * 128;

    // staging decomposition: lane i writes LDS at chunkBase + i*16
    const int srow   = lane >> 2;   // 0..15 row within 16-row chunk
    const int schunk = lane & 3;    // 16B chunk within a 64B row

    // hoisted staging pointers (incremented by 32 elements per K-iter)
    const __hip_bfloat16* aP[2];
    const __hip_bfloat16* bP[2];
    char* lA[2];
    char* lB[2];
    #pragma unroll
    for (int it = 0; it < 2; ++it) {
        int rchunk = it * 4 + wave;          // wave-uniform 16-row chunk id 0..7
        int row = rchunk * 16 + srow;        // 0..127
        aP[it] = A + (aBase + row) * DIM + schunk * 8;
        bP[it] = B + (bBase + row) * DIM + schunk * 8;
        lA[it] = ((char*)sA) + rchunk * 1024;
        lB[it] = ((char*)sB) + rchunk * 1024;
    }

    f32x4 acc[4][4] = {};

    for (int k0 = 0; k0 < DIM; k0 += 32) {
        __syncthreads();
        #pragma unroll
        for (int it = 0; it < 2; ++it) {
            glds16(aP[it], lA[it]);
            glds16(bP[it], lB[it]);
            aP[it] += 32;
            bP[it] += 32;
        }
        __syncthreads();

        bf16x8 af[4], bfr[4];
        #pragma unroll
        for (int mi = 0; mi < 4; ++mi)
            af[mi] = *(const bf16x8*)(sA + (wr * 64 + mi * 16 + l16) * 32 + q * 8);
        #pragma unroll
        for (int ni = 0; ni < 4; ++ni)
            bfr[ni] = *(const bf16x8*)(sB + (wc * 64 + ni * 16 + l16) * 32 + q * 8);

        #pragma unroll
        for (int mi = 0; mi < 4; ++mi)
            #pragma unroll
            for (int ni = 0; ni < 4; ++ni)
                acc[mi][ni] = __builtin_amdgcn_mfma_f32_16x16x32_bf16(
                    af[mi], bfr[ni], acc[mi][ni], 0, 0, 0);
    }

    // Branchless epilogue: every element treated as off-diagonal (label=-1):
    //   elem = softplus(z) = ln2 * log2(1 + exp2(z*log2e)),  z = scale*s + bias
    // Diagonal fixed up by diag_kernel (adds -z_ii per SigLip identity).
    const float l2e   = 1.44269504088896341f;
    const float scale = __expf(lscale[0]);
    const float aCo   = scale * l2e;
    const float bCo   = lbias[0] * l2e;
    float local = 0.0f;
    #pragma unroll
    for (int mi = 0; mi < 4; ++mi)
        #pragma unroll
        for (int ni = 0; ni < 4; ++ni)
            #pragma unroll
            for (int r = 0; r < 4; ++r) {
                float tl = fmaf(aCo, acc[mi][ni][r], bCo);
                local += flog2(1.0f + fexp2(tl));
            }

    #pragma unroll
    for (int off = 32; off > 0; off >>= 1) local += __shfl_down(local, off, 64);
    if (lane == 0) wred[wave] = local;
    __syncthreads();
    if (t == 0)
        atomicAdd(accum, (wred[0] + wred[1] + wred[2] + wred[3]) * 0.69314718055994531f);
}

__global__ void finalize_kernel(const float* __restrict__ accum, float* __restrict__ out) {
    out[0] = accum[0] / 268435456.0f;   // / N^2
}

extern "C" void kernel_launch(void* const* d_in, const int* in_sizes, int n_in,
                              void* d_out, int out_size, void* d_ws, size_t ws_size,
                              hipStream_t stream) {
    const float* img    = (const float*)d_in[0];
    const float* txt    = (const float*)d_in[1];
    const float* lscale = (const float*)d_in[2];
    const float* lbias  = (const float*)d_in[3];
    float* out = (float*)d_out;

    char* ws = (char*)d_ws;
    __hip_bfloat16* imgN = (__hip_bfloat16*)ws;
    __hip_bfloat16* txtN = (__hip_bfloat16*)(ws + (size_t)NROWS * DIM * 2);
    float* accum = (float*)(ws + (size_t)NROWS * DIM * 4);

    norm_kernel<<<dim3(NROWS, 2), 256, 0, stream>>>(img, txt, imgN, txtN, accum);
    diag_kernel<<<NROWS / 4, 256, 0, stream>>>(imgN, txtN, lscale, lbias, accum);
    siglip_gemm<<<dim3((NROWS / 128) * (NROWS / 128)), 256, 0, stream>>>(
        imgN, txtN, lscale, lbias, accum);
    finalize_kernel<<<1, 1, 0, stream>>>(accum, out);
}